// Round 1
// baseline (89.734 us; speedup 1.0000x reference)
//
#include <hip/hip_runtime.h>

#define CF 2048
#define TT 64
#define TP 65
#define KK 16
#define SS 4
#define EE 64
#define BB 2
#define DT_CONST 0.005f

// ws layout (floats)
#define COMB_OFF 0        // combined [4][64][16] = 4096
#define M_OFF    4096     // M [4][16][16] = 1024
#define PART_OFF 5120     // block partials [64][136] = 8704
#define WK_OFF   13824    // wk [2][64][16] = 2048  (16B aligned)

// ---------------- kernel 1: decay, combined, M[s] = mean_e c c^T ----------------
__global__ void k1_prep(const float* __restrict__ tc, const float* __restrict__ tk,
                        float* __restrict__ ws) {
    __shared__ float decay_s[SS][KK];
    __shared__ float comb_s[SS][EE][KK];
    int tid = threadIdx.x;
    if (tid < SS) {
        float inv = DT_CONST / tc[tid];
        float d[KK]; float sum = 0.f;
#pragma unroll
        for (int j = 0; j < KK; ++j) { d[j] = expf(-(float)j * inv); sum += d[j]; }
        float r = 1.f / sum;
#pragma unroll
        for (int j = 0; j < KK; ++j) decay_s[tid][j] = d[j] * r;
    }
    __syncthreads();
    {   // combined: thread = (s,e)
        int s = tid >> 6, e = tid & 63;
#pragma unroll
        for (int j = 0; j < KK; ++j) {
            float c = decay_s[s][j] * tk[(s * EE + e) * KK + j];
            comb_s[s][e][j] = c;
            ws[COMB_OFF + (s * EE + e) * KK + j] = c;
        }
    }
    __syncthreads();
    if (tid < SS * KK) {  // M: thread = (s,d1)
        int s = tid >> 4, d1 = tid & 15;
        float acc[KK];
#pragma unroll
        for (int j = 0; j < KK; ++j) acc[j] = 0.f;
        for (int e = 0; e < EE; ++e) {
            float cd1 = comb_s[s][e][d1];
#pragma unroll
            for (int d2 = 0; d2 < KK; ++d2) acc[d2] += cd1 * comb_s[s][e][d2];
        }
#pragma unroll
        for (int d2 = 0; d2 < KK; ++d2)
            ws[M_OFF + (s * KK + d1) * KK + d2] = acc[d2] * (1.f / 64.f);
    }
}

// ---------------- kernel 2: per-(b,cf) Gram pairs -> block partials ----------------
// grid 64 = 2 b * 32 cf-groups, block 512 = 8 waves * 64 lanes (lane = cf_local)
__global__ void k2_gram(const float* __restrict__ events, float* __restrict__ ws) {
    int b   = blockIdx.x >> 5;
    int cfg = blockIdx.x & 31;
    int lane = threadIdx.x & 63;
    int w    = threadIdx.x >> 6;    // wave id 0..7, handles pairs p%8==w
    int cf = cfg * 64 + lane;
    const float* xp = events + (size_t)(b * CF + cf) * TT;
    float x[TT];
#pragma unroll
    for (int i = 0; i < TT / 4; ++i) {
        float4 v = reinterpret_cast<const float4*>(xp)[i];
        x[4*i] = v.x; x[4*i+1] = v.y; x[4*i+2] = v.z; x[4*i+3] = v.w;
    }
    float tot = 0.f;
#pragma unroll
    for (int u = 0; u < TT; ++u) tot += x[u];
    // S1[d] = sum_t xpad[t+d] over the 65 valid t (total minus clipped edges)
    float S1[KK];
#pragma unroll
    for (int d = 0; d < KK; ++d) {
        float v = tot;
        if (d <= 7) {
#pragma unroll
            for (int u = d + 57; u < 64; ++u) v -= x[u];
        } else {
#pragma unroll
            for (int u = 0; u <= d - 9; ++u) v -= x[u];
        }
        S1[d] = v;
    }
    __shared__ float lds136[136];
    int p = 0;
#pragma unroll
    for (int d1 = 0; d1 < KK; ++d1) {
#pragma unroll
        for (int d2 = d1; d2 < KK; ++d2) {
            if ((p & 7) == w) {          // wave-uniform branch
                const int lag = d2 - d1;
                const int lo = (d1 - 8 > 0) ? d1 - 8 : 0;
                const int hi = ((63 - lag) < (d1 + 56)) ? (63 - lag) : (d1 + 56);
                float g = 0.f;
#pragma unroll
                for (int u = lo; u <= hi; ++u) g += x[u] * x[u + lag];
                g -= S1[d1] * S1[d2] * (1.f / 65.f);
#pragma unroll
                for (int sft = 1; sft < 64; sft <<= 1) g += __shfl_xor(g, sft, 64);
                if (lane == 0) lds136[p] = g;
            }
            ++p;
        }
    }
    __syncthreads();
    if (threadIdx.x < 136)
        ws[PART_OFF + blockIdx.x * 136 + threadIdx.x] = lds136[threadIdx.x];
}

// ---------------- kernel 3: reduce partials, fv, MLP, softmax, wk ----------------
__global__ void k3_mlp(const float* __restrict__ w1, const float* __restrict__ b1,
                       const float* __restrict__ w2, const float* __restrict__ b2,
                       float* __restrict__ ws) {
    __shared__ float Gsum[BB][136];
    __shared__ float fv_s[BB][SS];
    __shared__ float attn_s[BB][SS];
    int tid = threadIdx.x;
    for (int v = tid; v < BB * 136; v += 64) {
        int b = v / 136, pp = v % 136;
        float acc = 0.f;
        for (int blk = 0; blk < 32; ++blk)
            acc += ws[PART_OFF + (b * 32 + blk) * 136 + pp];
        Gsum[b][pp] = acc;
    }
    __syncthreads();
    if (tid < BB * SS) {
        int b = tid >> 2, s = tid & 3;
        float acc = 0.f;
        int p = 0;
        for (int d1 = 0; d1 < KK; ++d1)
            for (int d2 = d1; d2 < KK; ++d2) {
                float wgt = (d1 == d2) ? 1.f : 2.f;
                acc += wgt * ws[M_OFF + (s * KK + d1) * KK + d2] * Gsum[b][p];
                ++p;
            }
        fv_s[b][s] = acc * (1.f / (64.f * 2048.f));   // /(Tp-1) and /Cf
    }
    __syncthreads();
    if (tid < BB) {
        int b = tid;
        float h[8];
#pragma unroll
        for (int i = 0; i < 8; ++i) {
            float a = b1[i];
#pragma unroll
            for (int s = 0; s < SS; ++s) a += fv_s[b][s] * w1[i * SS + s];
            h[i] = a > 0.f ? a : 0.f;
        }
        float lg[SS]; float mx = -1e30f;
#pragma unroll
        for (int s = 0; s < SS; ++s) {
            float a = b2[s];
#pragma unroll
            for (int i = 0; i < 8; ++i) a += h[i] * w2[s * 8 + i];
            lg[s] = a; mx = fmaxf(mx, a);
        }
        float se = 0.f;
#pragma unroll
        for (int s = 0; s < SS; ++s) { lg[s] = expf(lg[s] - mx); se += lg[s]; }
#pragma unroll
        for (int s = 0; s < SS; ++s) attn_s[b][s] = lg[s] / se;
    }
    __syncthreads();
    for (int o = tid; o < BB * EE * KK; o += 64) {
        int b = o >> 10, e = (o >> 4) & 63, dt = o & 15;
        float a = 0.f;
#pragma unroll
        for (int s = 0; s < SS; ++s)
            a += attn_s[b][s] * ws[COMB_OFF + (s * EE + e) * KK + dt];
        ws[WK_OFF + o] = a;
    }
}

// ---------------- kernel 4: encoded[b,e,cf,t] = sum_dt wk[b,e,dt]*xpad[cf,t+dt] ----------------
__global__ void __launch_bounds__(256) k4_main(const float* __restrict__ events,
                                               const float* __restrict__ ws,
                                               float* __restrict__ out) {
    int g  = blockIdx.x * 256 + threadIdx.x;      // g = (b*64+e)*2048 + cf
    int cf = g & (CF - 1);
    int be = g >> 11;
    const float* wkp = ws + WK_OFF + be * KK;
    float wk[KK];
#pragma unroll
    for (int i = 0; i < KK / 4; ++i) {
        float4 v = reinterpret_cast<const float4*>(wkp)[i];
        wk[4*i] = v.x; wk[4*i+1] = v.y; wk[4*i+2] = v.z; wk[4*i+3] = v.w;
    }
    int b = be >> 6;
    const float* xp = events + (size_t)(b * CF + cf) * TT;
    float x[TT];
#pragma unroll
    for (int i = 0; i < TT / 4; ++i) {
        float4 v = reinterpret_cast<const float4*>(xp)[i];
        x[4*i] = v.x; x[4*i+1] = v.y; x[4*i+2] = v.z; x[4*i+3] = v.w;
    }
    float* op = out + (size_t)g * TP;
#pragma unroll
    for (int t = 0; t < TP; ++t) {
        float acc = 0.f;
#pragma unroll
        for (int dt = 0; dt < KK; ++dt) {
            const int u = t + dt - 8;
            if (u >= 0 && u < TT) acc += wk[dt] * x[u];
        }
        op[t] = acc;
    }
}

extern "C" void kernel_launch(void* const* d_in, const int* in_sizes, int n_in,
                              void* d_out, int out_size, void* d_ws, size_t ws_size,
                              hipStream_t stream) {
    const float* events = (const float*)d_in[0];
    const float* tc     = (const float*)d_in[1];
    const float* tk     = (const float*)d_in[2];
    const float* w1     = (const float*)d_in[3];
    const float* b1     = (const float*)d_in[4];
    const float* w2     = (const float*)d_in[5];
    const float* b2     = (const float*)d_in[6];
    float* out = (float*)d_out;
    float* ws  = (float*)d_ws;

    hipLaunchKernelGGL(k1_prep, dim3(1),    dim3(256), 0, stream, tc, tk, ws);
    hipLaunchKernelGGL(k2_gram, dim3(64),   dim3(512), 0, stream, events, ws);
    hipLaunchKernelGGL(k3_mlp,  dim3(1),    dim3(64),  0, stream, w1, b1, w2, b2, ws);
    hipLaunchKernelGGL(k4_main, dim3(1024), dim3(256), 0, stream, events, ws, out);
}

// Round 2
// 57.914 us; speedup vs baseline: 1.5494x; 1.5494x over previous
//
#include <hip/hip_runtime.h>

#define CF 2048
#define TT 64
#define TP 65
#define KK 16
#define SS 4
#define EE 64
#define BB 2
#define DT_CONST 0.005f

// ws layout (floats)
#define PART_OFF 0        // block partials [64][136] = 8704
#define WK_OFF   8704     // wk [2][64][16] = 2048

// ---------------- kernel 2: per-(b,cf) Gram pairs -> block partials ----------------
// grid 64 = 2 b * 32 cf-groups, block 512 = 8 waves * 64 lanes (lane = cf_local)
__global__ void k2_gram(const float* __restrict__ events, float* __restrict__ ws) {
    int b   = blockIdx.x >> 5;
    int cfg = blockIdx.x & 31;
    int lane = threadIdx.x & 63;
    int w    = threadIdx.x >> 6;    // wave id 0..7, handles pairs p%8==w
    int cf = cfg * 64 + lane;
    const float* xp = events + (size_t)(b * CF + cf) * TT;
    float x[TT];
#pragma unroll
    for (int i = 0; i < TT / 4; ++i) {
        float4 v = reinterpret_cast<const float4*>(xp)[i];
        x[4*i] = v.x; x[4*i+1] = v.y; x[4*i+2] = v.z; x[4*i+3] = v.w;
    }
    float tot = 0.f;
#pragma unroll
    for (int u = 0; u < TT; ++u) tot += x[u];
    // S1[d] = sum_t xpad[t+d] over the 65 valid t (total minus clipped edges)
    float S1[KK];
#pragma unroll
    for (int d = 0; d < KK; ++d) {
        float v = tot;
        if (d <= 7) {
#pragma unroll
            for (int u = d + 57; u < 64; ++u) v -= x[u];
        } else {
#pragma unroll
            for (int u = 0; u <= d - 9; ++u) v -= x[u];
        }
        S1[d] = v;
    }
    __shared__ float lds136[136];
    int p = 0;
#pragma unroll
    for (int d1 = 0; d1 < KK; ++d1) {
#pragma unroll
        for (int d2 = d1; d2 < KK; ++d2) {
            if ((p & 7) == w) {          // wave-uniform branch
                const int lag = d2 - d1;
                const int lo = (d1 - 8 > 0) ? d1 - 8 : 0;
                const int hi = ((63 - lag) < (d1 + 56)) ? (63 - lag) : (d1 + 56);
                float g = 0.f;
#pragma unroll
                for (int u = lo; u <= hi; ++u) g += x[u] * x[u + lag];
                g -= S1[d1] * S1[d2] * (1.f / 65.f);
#pragma unroll
                for (int sft = 1; sft < 64; sft <<= 1) g += __shfl_xor(g, sft, 64);
                if (lane == 0) lds136[p] = g;
            }
            ++p;
        }
    }
    __syncthreads();
    if (threadIdx.x < 136)
        ws[PART_OFF + blockIdx.x * 136 + threadIdx.x] = lds136[threadIdx.x];
}

// ---------------- kernel 3 (merged prep+mlp): decay, combined, M, Gsum, fv, MLP, wk ----------------
__global__ void k3_mlp(const float* __restrict__ tc, const float* __restrict__ tk,
                       const float* __restrict__ w1, const float* __restrict__ b1,
                       const float* __restrict__ w2, const float* __restrict__ b2,
                       float* __restrict__ ws) {
    __shared__ float decay_s[SS][KK];
    __shared__ float comb_s[SS][EE][KK];
    __shared__ float M_s[SS][KK][KK];
    __shared__ float Gsum[BB][136];
    __shared__ float fv_s[BB][SS];
    __shared__ float attn_s[BB][SS];
    int tid = threadIdx.x;
    if (tid < SS) {
        float inv = DT_CONST / tc[tid];
        float d[KK]; float sum = 0.f;
#pragma unroll
        for (int j = 0; j < KK; ++j) { d[j] = expf(-(float)j * inv); sum += d[j]; }
        float r = 1.f / sum;
#pragma unroll
        for (int j = 0; j < KK; ++j) decay_s[tid][j] = d[j] * r;
    }
    __syncthreads();
    {   // combined: thread = (s,e)
        int s = tid >> 6, e = tid & 63;
#pragma unroll
        for (int j = 0; j < KK; ++j)
            comb_s[s][e][j] = decay_s[s][j] * tk[(s * EE + e) * KK + j];
    }
    __syncthreads();
    if (tid < SS * KK) {  // M: thread = (s,d1)
        int s = tid >> 4, d1 = tid & 15;
        float acc[KK];
#pragma unroll
        for (int j = 0; j < KK; ++j) acc[j] = 0.f;
        for (int e = 0; e < EE; ++e) {
            float cd1 = comb_s[s][e][d1];
#pragma unroll
            for (int d2 = 0; d2 < KK; ++d2) acc[d2] += cd1 * comb_s[s][e][d2];
        }
#pragma unroll
        for (int d2 = 0; d2 < KK; ++d2) M_s[s][d1][d2] = acc[d2] * (1.f / 64.f);
    }
    // Gsum reduce (independent of M): do in same phase region, then sync
    for (int v = tid; v < BB * 136; v += 256) {
        int b = v / 136, pp = v % 136;
        float acc = 0.f;
        for (int blk = 0; blk < 32; ++blk)
            acc += ws[PART_OFF + (b * 32 + blk) * 136 + pp];
        Gsum[b][pp] = acc;
    }
    __syncthreads();
    if (tid < BB * SS) {
        int b = tid >> 2, s = tid & 3;
        float acc = 0.f;
        int p = 0;
        for (int d1 = 0; d1 < KK; ++d1)
            for (int d2 = d1; d2 < KK; ++d2) {
                float wgt = (d1 == d2) ? 1.f : 2.f;
                acc += wgt * M_s[s][d1][d2] * Gsum[b][p];
                ++p;
            }
        fv_s[b][s] = acc * (1.f / (64.f * 2048.f));   // /(Tp-1) and /Cf
    }
    __syncthreads();
    if (tid < BB) {
        int b = tid;
        float h[8];
#pragma unroll
        for (int i = 0; i < 8; ++i) {
            float a = b1[i];
#pragma unroll
            for (int s = 0; s < SS; ++s) a += fv_s[b][s] * w1[i * SS + s];
            h[i] = a > 0.f ? a : 0.f;
        }
        float lg[SS]; float mx = -1e30f;
#pragma unroll
        for (int s = 0; s < SS; ++s) {
            float a = b2[s];
#pragma unroll
            for (int i = 0; i < 8; ++i) a += h[i] * w2[s * 8 + i];
            lg[s] = a; mx = fmaxf(mx, a);
        }
        float se = 0.f;
#pragma unroll
        for (int s = 0; s < SS; ++s) { lg[s] = expf(lg[s] - mx); se += lg[s]; }
#pragma unroll
        for (int s = 0; s < SS; ++s) attn_s[b][s] = lg[s] / se;
    }
    __syncthreads();
    for (int o = tid; o < BB * EE * KK; o += 256) {
        int b = o >> 10, e = (o >> 4) & 63, dt = o & 15;
        float a = 0.f;
#pragma unroll
        for (int s = 0; s < SS; ++s)
            a += attn_s[b][s] * comb_s[s][e][dt];
        ws[WK_OFF + o] = a;
    }
}

// ---------------- kernel 4: encoded[b,e,cf,t] = sum_dt wk[b,e,dt]*xpad[cf,t+dt] ----------------
// block 256 rows -> LDS staging -> fully coalesced float4 writes of the block's
// contiguous 16640-float output span.
__global__ void __launch_bounds__(256) k4_main(const float* __restrict__ events,
                                               const float* __restrict__ ws,
                                               float* __restrict__ out) {
    __shared__ float buf[256 * TP];               // 66560 B
    int tid = threadIdx.x;
    int g  = blockIdx.x * 256 + tid;              // g = (b*64+e)*2048 + cf
    int cf = g & (CF - 1);
    int be = g >> 11;
    const float* wkp = ws + WK_OFF + be * KK;
    float wk[KK];
#pragma unroll
    for (int i = 0; i < KK / 4; ++i) {
        float4 v = reinterpret_cast<const float4*>(wkp)[i];
        wk[4*i] = v.x; wk[4*i+1] = v.y; wk[4*i+2] = v.z; wk[4*i+3] = v.w;
    }
    int b = be >> 6;
    const float* xp = events + (size_t)(b * CF + cf) * TT;
    float x[TT];
#pragma unroll
    for (int i = 0; i < TT / 4; ++i) {
        float4 v = reinterpret_cast<const float4*>(xp)[i];
        x[4*i] = v.x; x[4*i+1] = v.y; x[4*i+2] = v.z; x[4*i+3] = v.w;
    }
    float* bp = buf + tid * TP;
#pragma unroll
    for (int t = 0; t < TP; ++t) {
        float acc = 0.f;
#pragma unroll
        for (int dt = 0; dt < KK; ++dt) {
            const int u = t + dt - 8;
            if (u >= 0 && u < TT) acc += wk[dt] * x[u];
        }
        bp[t] = acc;
    }
    __syncthreads();
    const float4* bsrc = reinterpret_cast<const float4*>(buf);
    float4* odst = reinterpret_cast<float4*>(out + (size_t)blockIdx.x * (256 * TP));
#pragma unroll 4
    for (int j = tid; j < 256 * TP / 4; j += 256)
        odst[j] = bsrc[j];
}

extern "C" void kernel_launch(void* const* d_in, const int* in_sizes, int n_in,
                              void* d_out, int out_size, void* d_ws, size_t ws_size,
                              hipStream_t stream) {
    const float* events = (const float*)d_in[0];
    const float* tc     = (const float*)d_in[1];
    const float* tk     = (const float*)d_in[2];
    const float* w1     = (const float*)d_in[3];
    const float* b1     = (const float*)d_in[4];
    const float* w2     = (const float*)d_in[5];
    const float* b2     = (const float*)d_in[6];
    float* out = (float*)d_out;
    float* ws  = (float*)d_ws;

    hipLaunchKernelGGL(k2_gram, dim3(64),   dim3(512), 0, stream, events, ws);
    hipLaunchKernelGGL(k3_mlp,  dim3(1),    dim3(256), 0, stream, tc, tk, w1, b1, w2, b2, ws);
    hipLaunchKernelGGL(k4_main, dim3(1024), dim3(256), 0, stream, events, ws, out);
}